// Round 1
// baseline (90.704 us; speedup 1.0000x reference)
//
#include <hip/hip_runtime.h>

// SNN forward: IF neuron, T=64 timesteps.
//   c[t,b,o] = dot(x[t,b,:], W[o,:]) + b[o]
//   v += c; s = (v >= 1); v = s ? 0 : v; out = mean_t(s)
//
// Phase 1: GEMM over all 131072 (t,b) rows (memory-bound: 411 MB x-read).
// Phase 2: sequential membrane scan over t (5.2 MB, trivial).

#define T_STEPS 64
#define BATCH   2048
#define FEAT    784
#define OUT_N   10
#define M_ROWS  (T_STEPS * BATCH)   // 131072

// wave = 4 row-slots (r) x 16 f-lanes (l16); each lane accumulates G=4 rows.
// block = 256 threads = 4 waves = 64 rows. Grid = 131072/64 = 2048 blocks.
__global__ __launch_bounds__(256)
void snn_gemm(const float* __restrict__ x, const float* __restrict__ W,
              const float* __restrict__ bias, float* __restrict__ C) {
    __shared__ float Wl[OUT_N * FEAT];   // 31360 B

    // cooperative W load (tiny, one-time; L2-resident across blocks)
    for (int i = threadIdx.x; i < OUT_N * FEAT; i += 256) Wl[i] = W[i];
    __syncthreads();

    const int tid  = threadIdx.x;
    const int wave = tid >> 6;
    const int lane = tid & 63;
    const int l16  = lane & 15;       // f-slice within wave
    const int r    = lane >> 4;       // row slot
    const long gw   = (long)blockIdx.x * 4 + wave;  // global wave id, 0..8191
    const long row0 = gw * 16 + (long)r * 4;        // 4 consecutive rows per lane

    float acc[4][OUT_N];
#pragma unroll
    for (int g = 0; g < 4; ++g)
#pragma unroll
        for (int o = 0; o < OUT_N; ++o) acc[g][o] = 0.0f;

    const float* xbase = x + (size_t)row0 * FEAT + 4 * l16;

    // 12 full chunks of 64 features (lane covers floats 4*l16 .. 4*l16+3 of each chunk)
#pragma unroll
    for (int c = 0; c < 12; ++c) {
        float4 xf[4];
#pragma unroll
        for (int g = 0; g < 4; ++g)
            xf[g] = *(const float4*)(xbase + (size_t)g * FEAT + c * 64);
#pragma unroll
        for (int o = 0; o < OUT_N; ++o) {
            const float4 wf = *(const float4*)(&Wl[o * FEAT + 4 * l16 + c * 64]);
#pragma unroll
            for (int g = 0; g < 4; ++g) {
                acc[g][o] = fmaf(xf[g].x, wf.x, acc[g][o]);
                acc[g][o] = fmaf(xf[g].y, wf.y, acc[g][o]);
                acc[g][o] = fmaf(xf[g].z, wf.z, acc[g][o]);
                acc[g][o] = fmaf(xf[g].w, wf.w, acc[g][o]);
            }
        }
    }

    // tail: features 768..783 (16 floats) -> lanes l16 = 0..3
    if (l16 < 4) {
#pragma unroll
        for (int g = 0; g < 4; ++g) {
            const float4 xt = *(const float4*)(xbase + (size_t)g * FEAT + 768);
#pragma unroll
            for (int o = 0; o < OUT_N; ++o) {
                const float4 wf = *(const float4*)(&Wl[o * FEAT + 768 + 4 * l16]);
                acc[g][o] = fmaf(xt.x, wf.x, acc[g][o]);
                acc[g][o] = fmaf(xt.y, wf.y, acc[g][o]);
                acc[g][o] = fmaf(xt.z, wf.z, acc[g][o]);
                acc[g][o] = fmaf(xt.w, wf.w, acc[g][o]);
            }
        }
    }

    // reduce across the 16 f-lanes (xor masks 1,2,4,8 stay within the 16-group)
#pragma unroll
    for (int g = 0; g < 4; ++g)
#pragma unroll
        for (int o = 0; o < OUT_N; ++o) {
            float v = acc[g][o];
            v += __shfl_xor(v, 1, 64);
            v += __shfl_xor(v, 2, 64);
            v += __shfl_xor(v, 4, 64);
            v += __shfl_xor(v, 8, 64);
            acc[g][o] = v;
        }

    if (l16 == 0) {
#pragma unroll
        for (int g = 0; g < 4; ++g) {
            float* Cr = C + (size_t)(row0 + g) * OUT_N;
#pragma unroll
            for (int o = 0; o < OUT_N; ++o) Cr[o] = acc[g][o] + bias[o];
        }
    }
}

// Phase 2: one thread per (b, o); scan over t. Wave reads 256 B contiguous per t.
__global__ __launch_bounds__(256)
void snn_scan(const float* __restrict__ C, float* __restrict__ out) {
    const int idx = blockIdx.x * 256 + threadIdx.x;   // b*OUT_N + o
    if (idx >= BATCH * OUT_N) return;
    float v = 0.0f;
    float cnt = 0.0f;
#pragma unroll
    for (int t = 0; t < T_STEPS; ++t) {
        v += C[(size_t)t * BATCH * OUT_N + idx];
        if (v >= 1.0f) { cnt += 1.0f; v = 0.0f; }
    }
    out[idx] = cnt * (1.0f / 64.0f);
}

extern "C" void kernel_launch(void* const* d_in, const int* in_sizes, int n_in,
                              void* d_out, int out_size, void* d_ws, size_t ws_size,
                              hipStream_t stream) {
    const float* x    = (const float*)d_in[0];   // [64, 2048, 784] f32
    const float* W    = (const float*)d_in[1];   // [10, 784] f32
    const float* bias = (const float*)d_in[2];   // [10] f32
    float* out = (float*)d_out;                  // [2048, 10] f32
    float* C   = (float*)d_ws;                   // [131072, 10] f32 = 5.24 MB scratch

    snn_gemm<<<dim3(M_ROWS / 64), dim3(256), 0, stream>>>(x, W, bias, C);
    snn_scan<<<dim3((BATCH * OUT_N + 255) / 256), dim3(256), 0, stream>>>(C, out);
}